// Round 1
// baseline (1074.452 us; speedup 1.0000x reference)
//
#include <hip/hip_runtime.h>

#define DIM 2048
#define INTER 1408
#define NE 15
#define T_TOKENS 4096
#define NROUTED (T_TOKENS * 2)      // 8192 routed slots
#define NSLOT (NROUTED + T_TOKENS)  // + 4096 shared = 12288

using short8 = __attribute__((ext_vector_type(8))) short;
using f32x4  = __attribute__((ext_vector_type(4))) float;

__device__ inline unsigned short f2bf(float f) {
    return (unsigned short)((__float_as_uint(f) + 0x8000u) >> 16);
}
__device__ inline unsigned pk2bf(unsigned a, unsigned b) {
    // pack two fp32 (bit patterns) -> two bf16 (round-half-up), one v_perm
    return __builtin_amdgcn_perm(b + 0x8000u, a + 0x8000u, 0x07060302u);
}
__device__ inline uint4 cvt8(float4 f0, float4 f1) {
    uint4 r;
    r.x = pk2bf(__float_as_uint(f0.x), __float_as_uint(f0.y));
    r.y = pk2bf(__float_as_uint(f0.z), __float_as_uint(f0.w));
    r.z = pk2bf(__float_as_uint(f1.x), __float_as_uint(f1.y));
    r.w = pk2bf(__float_as_uint(f1.z), __float_as_uint(f1.w));
    return r;
}

// ---------------- x -> bf16 ----------------
__global__ void cvt_x_kernel(const float* __restrict__ x, unsigned short* __restrict__ xb) {
    int i = (blockIdx.x * 256 + threadIdx.x) * 4;
    float4 v = *(const float4*)(x + i);
    ushort4 o;
    o.x = f2bf(v.x); o.y = f2bf(v.y); o.z = f2bf(v.z); o.w = f2bf(v.w);
    *(ushort4*)(xb + i) = o;
}

// ---------------- gating: softmax over 15, top-2 ----------------
__global__ void gate_kernel(const float* __restrict__ x, const float* __restrict__ gw,
                            int* __restrict__ tk_idx, float* __restrict__ tk_w,
                            int* __restrict__ cnt) {
    int tok = blockIdx.x;
    int lane = threadIdx.x; // 64 threads
    const float* xr = x + (size_t)tok * DIM;
    float s[NE];
#pragma unroll
    for (int e = 0; e < NE; e++) s[e] = 0.f;
    for (int k = lane; k < DIM; k += 64) {
        float xv = xr[k];
#pragma unroll
        for (int e = 0; e < NE; e++) s[e] += xv * gw[e * DIM + k];
    }
#pragma unroll
    for (int e = 0; e < NE; e++) {
#pragma unroll
        for (int off = 32; off >= 1; off >>= 1) s[e] += __shfl_xor(s[e], off, 64);
    }
    if (lane == 0) {
        float mx = s[0];
#pragma unroll
        for (int e = 1; e < NE; e++) mx = fmaxf(mx, s[e]);
        float p[NE]; float den = 0.f;
#pragma unroll
        for (int e = 0; e < NE; e++) { p[e] = __expf(s[e] - mx); den += p[e]; }
        float inv = 1.f / den;
        int i0 = 0, i1 = -1; float b0 = p[0], b1 = -1.f;
#pragma unroll
        for (int e = 1; e < NE; e++) {
            float v = p[e];
            if (v > b0) { b1 = b0; i1 = i0; b0 = v; i0 = e; }
            else if (v > b1) { b1 = v; i1 = e; }
        }
        tk_idx[tok * 2] = i0;     tk_idx[tok * 2 + 1] = i1;
        tk_w[tok * 2] = b0 * inv; tk_w[tok * 2 + 1] = b1 * inv;
        atomicAdd(&cnt[i0], 1);   atomicAdd(&cnt[i1], 1);
    }
}

// ---------------- prefix offsets (16 segments incl. shared) ----------------
__global__ void offsets_kernel(int* __restrict__ cnt, int* __restrict__ off) {
    if (threadIdx.x == 0 && blockIdx.x == 0) {
        int a = 0;
        for (int e = 0; e < NE; e++) { off[e] = a; a += cnt[e]; }
        off[NE] = NROUTED;      // shared segment starts at 8192
        cnt[NE] = T_TOKENS;     // shared expert gets every token
    }
}

// ---------------- scatter tokens into slots ----------------
__global__ void scatter_kernel(const int* __restrict__ tk_idx, const float* __restrict__ tk_w,
                               const int* __restrict__ off, int* __restrict__ fill,
                               int* __restrict__ rows, float* __restrict__ rwt) {
    int id = blockIdx.x * 256 + threadIdx.x;
    if (id < NROUTED) {
        int e = tk_idx[id];
        int pos = off[e] + atomicAdd(&fill[e], 1);
        rows[pos] = id >> 1;
        rwt[pos] = tk_w[id];
    } else if (id < NSLOT) {
        int t = id - NROUTED;
        rows[NROUTED + t] = t;
        rwt[NROUTED + t] = 1.0f;
    }
}

// ---------------- GEMM1: H = silu(X w1^T) * (X w3^T), fused ----------------
// grid (11 n-tiles, 32 m-tiles, 16 experts), block 256 (4 waves, 2x2)
__global__ __launch_bounds__(256, 2)
void gemm1_kernel(const unsigned short* __restrict__ xb,
                  const float* __restrict__ w1, const float* __restrict__ w3,
                  const float* __restrict__ sw1, const float* __restrict__ sw3,
                  const int* __restrict__ rows, const int* __restrict__ off,
                  const int* __restrict__ cnt,
                  unsigned short* __restrict__ Ha) {
    __shared__ unsigned short As[128 * 32];
    __shared__ unsigned short B1s[128 * 32];
    __shared__ unsigned short B3s[128 * 32];
    __shared__ int rowLds[128];

    const int e = blockIdx.z;
    const int count = cnt[e];
    const int m0 = blockIdx.y * 128;
    if (m0 >= count) return;
    const int base = off[e];
    const int n0 = blockIdx.x * 128;

    const float* W1 = ((e < NE) ? (w1 + (size_t)e * INTER * DIM) : sw1) + (size_t)n0 * DIM;
    const float* W3 = ((e < NE) ? (w3 + (size_t)e * INTER * DIM) : sw3) + (size_t)n0 * DIM;

    const int tid = threadIdx.x;
    if (tid < 128) {
        int mi = m0 + tid;
        rowLds[tid] = rows[base + ((mi < count) ? mi : 0)];
    }
    __syncthreads();

    const int ar0 = tid >> 2, seg = tid & 3;
    const uint4* ap0 = (const uint4*)(xb + (size_t)rowLds[ar0] * DIM) + seg;
    const uint4* ap1 = (const uint4*)(xb + (size_t)rowLds[ar0 + 64] * DIM) + seg;
    const float4* b1p0 = (const float4*)(W1 + (size_t)ar0 * DIM) + seg * 2;
    const float4* b1p1 = (const float4*)(W1 + (size_t)(ar0 + 64) * DIM) + seg * 2;
    const float4* b3p0 = (const float4*)(W3 + (size_t)ar0 * DIM) + seg * 2;
    const float4* b3p1 = (const float4*)(W3 + (size_t)(ar0 + 64) * DIM) + seg * 2;

    uint4* aw0 = (uint4*)As + ar0 * 4 + seg;
    uint4* aw1 = (uint4*)As + (ar0 + 64) * 4 + seg;
    uint4* b1w0 = (uint4*)B1s + ar0 * 4 + seg;
    uint4* b1w1 = (uint4*)B1s + (ar0 + 64) * 4 + seg;
    uint4* b3w0 = (uint4*)B3s + ar0 * 4 + seg;
    uint4* b3w1 = (uint4*)B3s + (ar0 + 64) * 4 + seg;

    const int wave = tid >> 6, lane = tid & 63;
    const int wm = (wave >> 1) * 64, wn = (wave & 1) * 64;
    const int lr = lane & 15, lq = lane >> 4;
    const unsigned short* afp  = As  + (wm + lr) * 32 + lq * 8;
    const unsigned short* b1fp = B1s + (wn + lr) * 32 + lq * 8;
    const unsigned short* b3fp = B3s + (wn + lr) * 32 + lq * 8;

    f32x4 acc1[16], acc3[16];
    const f32x4 fz = {0.f, 0.f, 0.f, 0.f};
#pragma unroll
    for (int i = 0; i < 16; i++) { acc1[i] = fz; acc3[i] = fz; }

    for (int kt = 0; kt < DIM / 32; ++kt) {
        uint4 av0 = ap0[0], av1 = ap1[0];
        float4 f10a = b1p0[0], f10b = b1p0[1];
        float4 f11a = b1p1[0], f11b = b1p1[1];
        float4 f30a = b3p0[0], f30b = b3p0[1];
        float4 f31a = b3p1[0], f31b = b3p1[1];
        ap0 += 4; ap1 += 4;
        b1p0 += 8; b1p1 += 8; b3p0 += 8; b3p1 += 8;
        __syncthreads();
        *aw0 = av0; *aw1 = av1;
        *b1w0 = cvt8(f10a, f10b); *b1w1 = cvt8(f11a, f11b);
        *b3w0 = cvt8(f30a, f30b); *b3w1 = cvt8(f31a, f31b);
        __syncthreads();
        short8 af[4], b1f[4], b3f[4];
#pragma unroll
        for (int i = 0; i < 4; i++) af[i] = *(const short8*)(afp + i * 16 * 32);
#pragma unroll
        for (int j = 0; j < 4; j++) {
            b1f[j] = *(const short8*)(b1fp + j * 16 * 32);
            b3f[j] = *(const short8*)(b3fp + j * 16 * 32);
        }
#pragma unroll
        for (int i = 0; i < 4; i++)
#pragma unroll
            for (int j = 0; j < 4; j++) {
                acc1[i * 4 + j] = __builtin_amdgcn_mfma_f32_16x16x32_bf16(af[i], b1f[j], acc1[i * 4 + j], 0, 0, 0);
                acc3[i * 4 + j] = __builtin_amdgcn_mfma_f32_16x16x32_bf16(af[i], b3f[j], acc3[i * 4 + j], 0, 0, 0);
            }
    }

    // fused SiLU epilogue -> Ha (bf16)
#pragma unroll
    for (int i = 0; i < 4; i++) {
#pragma unroll
        for (int t = 0; t < 4; t++) {
            int lm = wm + i * 16 + lq * 4 + t;
            int mi = m0 + lm;
            if (mi < count) {
                size_t rowbase = (size_t)(base + mi) * INTER + n0 + wn + lr;
#pragma unroll
                for (int j = 0; j < 4; j++) {
                    float h1 = acc1[i * 4 + j][t];
                    float h3 = acc3[i * 4 + j][t];
                    float hv = h1 / (1.f + __expf(-h1)) * h3;
                    Ha[rowbase + j * 16] = f2bf(hv);
                }
            }
        }
    }
}

// ---------------- GEMM2: out += rwt * (H w2^T) ----------------
// grid (16 n-tiles, 32 m-tiles, 16 experts), block 256
__global__ __launch_bounds__(256, 2)
void gemm2_kernel(const unsigned short* __restrict__ Ha,
                  const float* __restrict__ w2, const float* __restrict__ sw2,
                  const int* __restrict__ rows, const float* __restrict__ rwt,
                  const int* __restrict__ off, const int* __restrict__ cnt,
                  float* __restrict__ out) {
    __shared__ unsigned short As[128 * 32];
    __shared__ unsigned short Bs[128 * 32];
    __shared__ int tokLds[128];
    __shared__ float wtLds[128];

    const int e = blockIdx.z;
    const int count = cnt[e];
    const int m0 = blockIdx.y * 128;
    if (m0 >= count) return;
    const int base = off[e];
    const int n0 = blockIdx.x * 128;
    const int s0 = base + m0;

    const float* W2 = ((e < NE) ? (w2 + (size_t)e * DIM * INTER) : sw2) + (size_t)n0 * INTER;

    const int tid = threadIdx.x;
    if (tid < 128) {
        tokLds[tid] = rows[s0 + tid];
        wtLds[tid] = rwt[s0 + tid];
    }

    const int ar0 = tid >> 2, seg = tid & 3;
    const uint4* ap0 = (const uint4*)(Ha + (size_t)(s0 + ar0) * INTER) + seg;
    const uint4* ap1 = (const uint4*)(Ha + (size_t)(s0 + ar0 + 64) * INTER) + seg;
    const float4* bp0 = (const float4*)(W2 + (size_t)ar0 * INTER) + seg * 2;
    const float4* bp1 = (const float4*)(W2 + (size_t)(ar0 + 64) * INTER) + seg * 2;
    uint4* aw0 = (uint4*)As + ar0 * 4 + seg;
    uint4* aw1 = (uint4*)As + (ar0 + 64) * 4 + seg;
    uint4* bw0 = (uint4*)Bs + ar0 * 4 + seg;
    uint4* bw1 = (uint4*)Bs + (ar0 + 64) * 4 + seg;

    const int wave = tid >> 6, lane = tid & 63;
    const int wm = (wave >> 1) * 64, wn = (wave & 1) * 64;
    const int lr = lane & 15, lq = lane >> 4;
    const unsigned short* afp = As + (wm + lr) * 32 + lq * 8;
    const unsigned short* bfp = Bs + (wn + lr) * 32 + lq * 8;

    f32x4 acc[16];
    const f32x4 fz = {0.f, 0.f, 0.f, 0.f};
#pragma unroll
    for (int i = 0; i < 16; i++) acc[i] = fz;

    for (int kt = 0; kt < INTER / 32; ++kt) {
        uint4 av0 = ap0[0], av1 = ap1[0];
        float4 f0a = bp0[0], f0b = bp0[1];
        float4 f1a = bp1[0], f1b = bp1[1];
        ap0 += 4; ap1 += 4; bp0 += 8; bp1 += 8;
        __syncthreads();
        *aw0 = av0; *aw1 = av1;
        *bw0 = cvt8(f0a, f0b); *bw1 = cvt8(f1a, f1b);
        __syncthreads();
        short8 af[4], bf_[4];
#pragma unroll
        for (int i = 0; i < 4; i++) af[i] = *(const short8*)(afp + i * 16 * 32);
#pragma unroll
        for (int j = 0; j < 4; j++) bf_[j] = *(const short8*)(bfp + j * 16 * 32);
#pragma unroll
        for (int i = 0; i < 4; i++)
#pragma unroll
            for (int j = 0; j < 4; j++)
                acc[i * 4 + j] = __builtin_amdgcn_mfma_f32_16x16x32_bf16(af[i], bf_[j], acc[i * 4 + j], 0, 0, 0);
    }

#pragma unroll
    for (int i = 0; i < 4; i++) {
#pragma unroll
        for (int t = 0; t < 4; t++) {
            int lm = wm + i * 16 + lq * 4 + t;
            int mi = m0 + lm;
            if (mi < count) {
                float wgt = wtLds[lm];
                float* orow = out + (size_t)tokLds[lm] * DIM + n0 + wn + lr;
#pragma unroll
                for (int j = 0; j < 4; j++)
                    atomicAdd(orow + j * 16, acc[i * 4 + j][t] * wgt);
            }
        }
    }
}

extern "C" void kernel_launch(void* const* d_in, const int* in_sizes, int n_in,
                              void* d_out, int out_size, void* d_ws, size_t ws_size,
                              hipStream_t stream) {
    const float* x   = (const float*)d_in[0];
    const float* gw  = (const float*)d_in[1];
    const float* w1  = (const float*)d_in[2];
    const float* w3  = (const float*)d_in[3];
    const float* w2  = (const float*)d_in[4];
    const float* sw1 = (const float*)d_in[5];
    const float* sw3 = (const float*)d_in[6];
    const float* sw2 = (const float*)d_in[7];
    float* out = (float*)d_out;

    char* p = (char*)d_ws;
    unsigned short* xb = (unsigned short*)p; p += (size_t)T_TOKENS * DIM * 2;   // 16 MB
    unsigned short* Ha = (unsigned short*)p; p += (size_t)NSLOT * INTER * 2;    // 33 MB
    int*   rows   = (int*)p;   p += NSLOT * 4;
    float* rwt    = (float*)p; p += NSLOT * 4;
    int*   tk_idx = (int*)p;   p += NROUTED * 4;
    float* tk_w   = (float*)p; p += NROUTED * 4;
    int*   cnt    = (int*)p;   p += 64;
    int*   fill   = (int*)p;   p += 64;
    int*   off    = (int*)p;   p += 64;

    hipMemsetAsync(cnt, 0, 192, stream);                                   // cnt+fill+off
    hipMemsetAsync(out, 0, (size_t)T_TOKENS * DIM * 4, stream);

    cvt_x_kernel<<<8192, 256, 0, stream>>>(x, xb);
    gate_kernel<<<T_TOKENS, 64, 0, stream>>>(x, gw, tk_idx, tk_w, cnt);
    offsets_kernel<<<1, 64, 0, stream>>>(cnt, off);
    scatter_kernel<<<NSLOT / 256, 256, 0, stream>>>(tk_idx, tk_w, off, fill, rows, rwt);
    gemm1_kernel<<<dim3(11, 32, 16), 256, 0, stream>>>(xb, w1, w3, sw1, sw3, rows, off, cnt, Ha);
    gemm2_kernel<<<dim3(16, 32, 16), 256, 0, stream>>>(Ha, w2, sw2, rows, rwt, off, cnt, out);
}